// Round 7
// baseline (408.689 us; speedup 1.0000x reference)
//
#include <hip/hip_runtime.h>
#include <cmath>
#include <cstdint>
#include <cstring>

// Problem constants (B,C,H,W) = (16,3,512,512), window 11, patch 16.
#define OUTD 502          // 512 - 11 + 1
#define TSX  64           // output tile width
#define TSY  32           // output tile height (2 groups of 16)
#define HT2P   20         // transpose buffer row pitch (f16): 40 B
#define NTAP 11
#define GX   8            // ceil(502/64)
#define GY   16           // ceil(502/32)
#define NPARTIAL (48 * GY * GX)   // 6144
#define TOTBLK NPARTIAL

typedef float    f32x2 __attribute__((ext_vector_type(2)));
typedef float    f32x4 __attribute__((ext_vector_type(4)));
typedef _Float16 f16x4 __attribute__((ext_vector_type(4)));
typedef _Float16 f16x8 __attribute__((ext_vector_type(8)));
typedef __attribute__((address_space(3))) const _Float16 lds_cf16;

struct GW { float g[NTAP]; float cm; };  // g: fp16-rounded weights; cm = 1/(sum g)^2

__device__ __forceinline__ f32x4 mfma_f16(f16x8 a, f16x8 b, f32x4 c) {
    return __builtin_amdgcn_mfma_f32_16x16x32_f16(a, b, c, 0, 0, 0);
}

// Fused kernel: per-block mask dilation + MFMA separable-Gaussian SSIM over a
// 64x32 tile + last-block grid finalize. R7 rationale: total-minus-ssim time
// has been a CONSTANT ~104 us across R0-R6 (patch_max launch ~10-15 us at 2
// blocks/CU, 1-block finalize ~5-8 us with the GPU idle, plus inter-kernel
// bubbles) -- now 62% of total. ssim itself is latency-plateaued at ~62 us
// (all pipes <50%), so this round removes the other two launches:
//  (a) dilation fused: each block computes its 15 sdil entries from mask
//      directly (35 patch-maxes over its 5x7 patch neighborhood; 560 row
//      tasks of 4x int4; LDS atomicMax). Mask is L3-resident; pipes are idle.
//  (b) finalize fused: partial + threadfence + atomicAdd(counter); the block
//      seeing old==TOTBLK-1 re-reads partials in the same fixed order as the
//      old finalize_kernel (deterministic) and writes out. counter is zeroed
//      by a 4-byte hipMemsetAsync in kernel_launch (capture-legal).
// Main SSIM pipeline (direct global->reg B-frags, Toeplitz-MFMA H-conv,
// row-major sHT + ds_read_b64_tr_b16 V-conv, packed f32x2 epilogue) is
// byte-identical to R6's verified structure.
__global__ __launch_bounds__(256) void ssim_fused(const float* __restrict__ img1,
                                                  const float* __restrict__ img2,
                                                  const int* __restrict__ mask,
                                                  float* __restrict__ partial,
                                                  unsigned int* __restrict__ counter,
                                                  float* __restrict__ out, GW gw) {
    __shared__ __align__(16) _Float16 sHT[4][48][HT2P];   // 7680 B per-wave H-results
    __shared__ _Float16 gpad[48];               // zero-padded taps: gpad[15+i]=g[i]
    __shared__ int pm[35];                      // 5x7 patch-max neighborhood
    __shared__ int sdil[15];                    // 3 patch-rows x 5 patch-cols
    __shared__ float wsum[4];
    __shared__ int lastflag;
    __shared__ double sd[256];

    const int tid  = threadIdx.x;
    const int wv   = tid >> 6, lane = tid & 63;
    const int nidx = lane & 15, quad = lane >> 4;
    const int x0 = blockIdx.x * TSX, y0 = blockIdx.y * TSY;
    const int bc = blockIdx.z;               // b*3 + c
    const size_t base = (size_t)bc << 18;    // *512*512

    // This wave handles output cols cb..cb+15 of the tile.
    const int cb = 16 * wv;

    // Direct global->reg B-frags (issued early; consumed after the syncs).
    // Clamps: col base <=504 (8 f32 stay in-row), row <=511. Clamped data
    // only feeds zero-weighted taps or discarded outputs, and is finite.
    int gxc = x0 + cb + quad * 8; gxc = gxc > 504 ? 504 : gxc;
    f16x8 fa[3], fb[3];
    #pragma unroll
    for (int h = 0; h < 3; ++h) {
        int gy = y0 + 16 * h + nidx; gy = gy > 511 ? 511 : gy;
        const float* p1 = img1 + base + ((size_t)gy << 9) + gxc;
        const float* p2 = img2 + base + ((size_t)gy << 9) + gxc;
        f32x4 alo = *(const f32x4*)p1, ahi = *(const f32x4*)(p1 + 4);
        f32x4 blo = *(const f32x4*)p2, bhi = *(const f32x4*)(p2 + 4);
        f16x4 al = __builtin_convertvector(alo, f16x4);
        f16x4 ah = __builtin_convertvector(ahi, f16x4);
        f16x4 bl = __builtin_convertvector(blo, f16x4);
        f16x4 bh = __builtin_convertvector(bhi, f16x4);
        fa[h] = __builtin_shufflevector(al, ah, 0, 1, 2, 3, 4, 5, 6, 7);
        fb[h] = __builtin_shufflevector(bl, bh, 0, 1, 2, 3, 4, 5, 6, 7);
    }

    // LDS init (disjoint thread ranges run in parallel)
    if (tid < 35) pm[tid] = 0;
    else if (tid >= 64 && tid < 112) {
        // padded tap table (indices 15..25 hold g[0..10], rest zero)
        int t = tid - 64;
        int k = t - 15;
        int kc = k < 0 ? 0 : (k > 10 ? 10 : k);      // clamp: no speculative OOB
        gpad[t] = (k == kc) ? (_Float16)gw.g[kc] : (_Float16)0.f;
    } else if (tid == 192) lastflag = 0;
    __syncthreads();

    // Fused patch-max: tile needs patches rows 2by-1..2by+3, cols 4bx-1..4bx+5.
    // 560 tasks = 35 patches x 16 rows; each task max-reduces one 16-int row.
    {
        const int* mbase = mask + ((size_t)(bc / 3) << 18);
        #pragma unroll
        for (int T = tid; T < 560; T += 256) {
            int p = T >> 4, i = T & 15;
            int pr = 2 * (int)blockIdx.y - 1 + p / 7;
            int pc = 4 * (int)blockIdx.x - 1 + p % 7;
            if (pr >= 0 && pr < 32 && pc >= 0 && pc < 32) {
                const int4* r4 = (const int4*)(mbase + (((pr << 4) + i) << 9) + (pc << 4));
                int4 v0 = r4[0], v1 = r4[1], v2 = r4[2], v3 = r4[3];
                int m = max(max(max(v0.x, v0.y), max(v0.z, v0.w)),
                            max(max(v1.x, v1.y), max(v1.z, v1.w)));
                m = max(m, max(max(max(v2.x, v2.y), max(v2.z, v2.w)),
                               max(max(v3.x, v3.y), max(v3.z, v3.w))));
                if (m) atomicMax(&pm[p], 1);
            }
        }
    }
    __syncthreads();

    // 3x3 dilation from the pm grid (pm is offset by (-1,-1) patches)
    if (tid < 15) {
        int tr = tid / 5, tc = tid - tr * 5;
        int acc = 0;
        #pragma unroll
        for (int dy = 0; dy < 3; ++dy)
            #pragma unroll
            for (int dx = 0; dx < 3; ++dx) acc |= pm[(tr + dy) * 7 + tc + dx];
        sdil[tid] = acc ? 1 : 0;
    }
    __syncthreads();

    // Toeplitz A-frag (shared by all passes): A[m=nidx][k=quad*8+j] = g[k-m].
    f16x8 af;
    {
        const _Float16* gp = &gpad[quad * 8 - nidx + 15];
        #pragma unroll
        for (int j = 0; j < 8; ++j) af[j] = gp[j];
    }

    // Transpose-buffer addresses (per-wave region sHT[wv], 40 B rows):
    // write: lane(quad,nidx) holds (x' = 4*quad+r, y = 16g+nidx) -> word at
    //        row 16g+nidx, col 4*quad  (one b64 per g; +320 f16 per g).
    _Float16* wp = &sHT[wv][nidx][quad * 4];
    // tr read: lane(q,m) fetches word (y = 8q + (m>>2) [+4h +16G], w = m&3).
    lds_cf16* rp = (lds_cf16*)&sHT[wv][8 * quad + (nidx >> 2)][4 * (nidx & 3)];

    // Per map: 3 H-MFMAs -> row-major sHT -> tr-read -> 2 V-MFMAs.
    f32x4 acca[4], accb[4];
    #pragma unroll
    for (int mm = 0; mm < 4; ++mm) {
        f16x8 f0, f1, f2;
        if (mm == 0)      { f0 = fa[0]; f1 = fa[1]; f2 = fa[2]; }
        else if (mm == 1) { f0 = fb[0]; f1 = fb[1]; f2 = fb[2]; }
        else if (mm == 2) { f0 = fa[0] * fb[0]; f1 = fa[1] * fb[1]; f2 = fa[2] * fb[2]; }
        else              { f0 = fa[0] * fa[0] + fb[0] * fb[0];
                            f1 = fa[1] * fa[1] + fb[1] * fb[1];
                            f2 = fa[2] * fa[2] + fb[2] * fb[2]; }
        f32x4 z = {0.f, 0.f, 0.f, 0.f};
        f32x4 c0 = mfma_f16(af, f0, z);   // H-conv rows 0..15
        f32x4 c1 = mfma_f16(af, f1, z);   // rows 16..31
        f32x4 c2 = mfma_f16(af, f2, z);   // rows 32..47
        // C layout: x' = quad*4+r (consecutive r!), y = data row = nidx + 16g
        *(f16x4*)(wp)       = __builtin_convertvector(c0, f16x4);
        *(f16x4*)(wp + 320) = __builtin_convertvector(c1, f16x4);
        *(f16x4*)(wp + 640) = __builtin_convertvector(c2, f16x4);
        // V-pass B-frags via HW transpose read. offsets (bytes):
        //   group a (y=0..31):  h0 -> 0,   h1 -> +4 rows = 160
        //   group b (y=16..47): h0 -> 640, h1 -> 800
        f16x4 r0, r1, r2, r3;
        asm volatile("ds_read_b64_tr_b16 %0, %4 offset:0\n\t"
                     "ds_read_b64_tr_b16 %1, %4 offset:160\n\t"
                     "ds_read_b64_tr_b16 %2, %4 offset:640\n\t"
                     "ds_read_b64_tr_b16 %3, %4 offset:800"
                     : "=&v"(r0), "=&v"(r1), "=&v"(r2), "=&v"(r3)
                     : "v"(rp) : "memory");
        asm volatile("s_waitcnt lgkmcnt(0)" ::: "memory");
        __builtin_amdgcn_sched_barrier(0);   // rule #18: keep MFMA after the wait
        f16x8 hba = __builtin_shufflevector(r0, r1, 0, 1, 2, 3, 4, 5, 6, 7);
        f16x8 hbb = __builtin_shufflevector(r2, r3, 0, 1, 2, 3, 4, 5, 6, 7);
        acca[mm] = mfma_f16(af, hba, z);
        accb[mm] = mfma_f16(af, hbb, z);
    }

    // Epilogue: lane holds 4 maps x 8 pixels: group a at y = y0+quad*4+r,
    // group b at y = y0+16+quad*4+r, x = x0+cb+nidx. f32x2 packs (a,b).
    const float C1v = 1e-4f, C2v = 9e-4f;  // L = 1 (inputs uniform [0,1))
    const float cm = gw.cm;
    float lsum = 0.f;
    {
        const int xl = cb + nidx;
        const int x = x0 + xl;
        if (x < OUTD) {
            const int lc0 = xl >> 4, lc1 = (xl + 10) >> 4;
            const int p0 = sdil[lc0]      & sdil[lc1];
            const int p1 = sdil[5 + lc0]  & sdil[5 + lc1];
            const int p2 = sdil[10 + lc0] & sdil[10 + lc1];

            #pragma unroll
            for (int r = 0; r < 4; ++r) {
                int q4r = quad * 4 + r;
                int cond = q4r < 6;   // window stays within patch-row stripe
                int va = cond ? p0 : (p0 & p1);              // group a always in-range
                int yb = y0 + 16 + q4r;
                int vb = cond ? p1 : (p1 & p2);
                vb = (yb < OUTD) ? vb : 0;
                f32x2 mu1 = {acca[0][r], accb[0][r]};
                f32x2 mu2 = {acca[1][r], accb[1][r]};
                f32x2 Sab = {acca[2][r], accb[2][r]};
                f32x2 Sss = {acca[3][r], accb[3][r]};
                mu1 *= cm; mu2 *= cm; Sab *= cm; Sss *= cm;
                f32x2 mu1s = mu1 * mu1, mu2s = mu2 * mu2, mu12 = mu1 * mu2;
                f32x2 sg12 = Sab - mu12;
                f32x2 sigS = Sss - mu1s - mu2s;
                f32x2 num = (2.f * mu12 + C1v) * (2.f * sg12 + C2v);
                f32x2 den = (mu1s + mu2s + C1v) * (sigS + C2v);
                if (va) lsum += __fdividef(num[0], den[0]);
                if (vb) lsum += __fdividef(num[1], den[1]);
            }
        }
    }

    // block reduction -> one float partial per block (deterministic, no atomics)
    #pragma unroll
    for (int off = 32; off >= 1; off >>= 1) lsum += __shfl_xor(lsum, off);
    if ((tid & 63) == 0) wsum[tid >> 6] = lsum;
    __syncthreads();
    if (tid == 0) {
        partial[((int)blockIdx.z * GY + (int)blockIdx.y) * GX + (int)blockIdx.x] =
            wsum[0] + wsum[1] + wsum[2] + wsum[3];
        __threadfence();                          // release partial before count
        unsigned int old = atomicAdd(counter, 1u);
        if (old == TOTBLK - 1) lastflag = 1;
    }
    __syncthreads();

    // Last block: deterministic grid reduction (same order as old finalize)
    if (lastflag) {
        __threadfence();                          // acquire all partials
        double s = 0.0;
        const f32x4* p4 = (const f32x4*)partial;
        for (int i = tid; i < NPARTIAL / 4; i += 256) {
            f32x4 vv = p4[i];
            s += (double)vv.x + (double)vv.y + (double)vv.z + (double)vv.w;
        }
        sd[tid] = s;
        __syncthreads();
        for (int st = 128; st >= 1; st >>= 1) {
            if (tid < st) sd[tid] += sd[tid + st];
            __syncthreads();
        }
        if (tid == 0) out[0] = (float)(sd[0] / 12096192.0);  // 16*3*502*502
    }
}

// Round a positive normal double to the nearest fp16-representable float (RTNE).
static inline float fp16_rtne(double x) {
    float f = (float)x;
    uint32_t u; memcpy(&u, &f, 4);
    // drop 13 mantissa bits (23 -> 10), RTNE with carry into exponent
    u = (u + 0xFFFu + ((u >> 13) & 1u)) & ~0x1FFFu;
    memcpy(&f, &u, 4);
    return f;
}

extern "C" void kernel_launch(void* const* d_in, const int* in_sizes, int n_in,
                              void* d_out, int out_size, void* d_ws, size_t ws_size,
                              hipStream_t stream) {
    const float* img1 = (const float*)d_in[0];
    const float* img2 = (const float*)d_in[1];
    const int*   mask = (const int*)d_in[2];
    float* out = (float*)d_out;

    char* ws = (char*)d_ws;
    float* partial = (float*)ws;                              // 6144 floats
    unsigned int* counter = (unsigned int*)(ws + NPARTIAL * 4);

    // Gaussian(sigma=1.5), normalized in double, then each tap rounded to
    // fp16 (RTNE). cm = 1/(sum of rounded taps)^2 removes the systematic
    // scale error of fp16 conv weights (applied to all 4 maps in epilogue).
    GW gw;
    double gd[NTAP], gsum = 0.0;
    for (int i = 0; i < NTAP; ++i) {
        double x = (double)(i - 5);
        gd[i] = exp(-(x * x) / 4.5);
        gsum += gd[i];
    }
    double wsumr = 0.0;
    for (int i = 0; i < NTAP; ++i) {
        gw.g[i] = fp16_rtne(gd[i] / gsum);
        wsumr += (double)gw.g[i];
    }
    gw.cm = (float)(1.0 / (wsumr * wsumr));

    // zero the grid-completion counter (graph-capture-legal async memset)
    hipMemsetAsync(counter, 0, sizeof(unsigned int), stream);
    ssim_fused<<<dim3(GX, GY, 48), 256, 0, stream>>>(img1, img2, mask,
                                                     partial, counter, out, gw);
}

// Round 8
// 170.775 us; speedup vs baseline: 2.3931x; 2.3931x over previous
//
#include <hip/hip_runtime.h>
#include <cmath>
#include <cstdint>
#include <cstring>

// Problem constants (B,C,H,W) = (16,3,512,512), window 11, patch 16.
#define OUTD 502          // 512 - 11 + 1
#define TSX  64           // output tile width
#define TSY  32           // output tile height (2 groups of 16)
#define HT2P   20         // transpose buffer row pitch (f16): 40 B
#define NTAP 11
#define GX   8            // ceil(502/64)
#define GY   16           // ceil(502/32)
#define NPARTIAL (48 * GY * GX)   // 6144

typedef float    f32x2 __attribute__((ext_vector_type(2)));
typedef float    f32x4 __attribute__((ext_vector_type(4)));
typedef _Float16 f16x4 __attribute__((ext_vector_type(4)));
typedef _Float16 f16x8 __attribute__((ext_vector_type(8)));
typedef __attribute__((address_space(3))) const _Float16 lds_cf16;

struct GW { float g[NTAP]; float cm; };  // g: fp16-rounded weights; cm = 1/(sum g)^2

__device__ __forceinline__ f32x4 mfma_f16(f16x8 a, f16x8 b, f32x4 c) {
    return __builtin_amdgcn_mfma_f32_16x16x32_f16(a, b, c, 0, 0, 0);
}

// Fused kernel: per-block mask patch-max+dilation + MFMA separable-Gaussian
// SSIM over a 64x32 tile. R8 rationale: R7's 5x regression (313 us, all pipes
// idle) is attributed to the finalize-fusion's per-block device-scope
// __threadfence() -- on gfx950 the per-XCD L2s are non-coherent, so a
// device release fence costs an L2 writeback; 6144 of them serialize at the
// 8 XCDs. That path is REVERTED (separate deterministic finalize kernel, no
// fences/atomics/counter). R7 also showed overhead is ~95 us FIXED harness
// cost (single-kernel overhead 95.7 vs 3-kernel 103.6), so fusion's value is
// only ~8 us -- patch-max fusion is kept (removes one launch) but made
// cheaper: 16-lane shfl_xor max reduce + plain pm store, no LDS atomics.
// SSIM pipeline (direct global->reg B-frags, Toeplitz-MFMA H-conv, row-major
// sHT + ds_read_b64_tr_b16 V-conv, packed f32x2 epilogue) is R6-identical.
__global__ __launch_bounds__(256) void ssim_fused(const float* __restrict__ img1,
                                                  const float* __restrict__ img2,
                                                  const int* __restrict__ mask,
                                                  float* __restrict__ partial, GW gw) {
    __shared__ __align__(16) _Float16 sHT[4][48][HT2P];   // 7680 B per-wave H-results
    __shared__ _Float16 gpad[48];               // zero-padded taps: gpad[15+i]=g[i]
    __shared__ int pm[35];                      // 5x7 patch-max neighborhood
    __shared__ int sdil[15];                    // 3 patch-rows x 5 patch-cols
    __shared__ float wsum[4];

    const int tid  = threadIdx.x;
    const int wv   = tid >> 6, lane = tid & 63;
    const int nidx = lane & 15, quad = lane >> 4;
    const int x0 = blockIdx.x * TSX, y0 = blockIdx.y * TSY;
    const int bc = blockIdx.z;               // b*3 + c
    const size_t base = (size_t)bc << 18;    // *512*512

    // This wave handles output cols cb..cb+15 of the tile.
    const int cb = 16 * wv;

    // Direct global->reg B-frags (issued early; consumed after the sync).
    // Clamps: col base <=504 (8 f32 stay in-row), row <=511. Clamped data
    // only feeds zero-weighted taps or discarded outputs, and is finite.
    int gxc = x0 + cb + quad * 8; gxc = gxc > 504 ? 504 : gxc;
    f16x8 fa[3], fb[3];
    #pragma unroll
    for (int h = 0; h < 3; ++h) {
        int gy = y0 + 16 * h + nidx; gy = gy > 511 ? 511 : gy;
        const float* p1 = img1 + base + ((size_t)gy << 9) + gxc;
        const float* p2 = img2 + base + ((size_t)gy << 9) + gxc;
        f32x4 alo = *(const f32x4*)p1, ahi = *(const f32x4*)(p1 + 4);
        f32x4 blo = *(const f32x4*)p2, bhi = *(const f32x4*)(p2 + 4);
        f16x4 al = __builtin_convertvector(alo, f16x4);
        f16x4 ah = __builtin_convertvector(ahi, f16x4);
        f16x4 bl = __builtin_convertvector(blo, f16x4);
        f16x4 bh = __builtin_convertvector(bhi, f16x4);
        fa[h] = __builtin_shufflevector(al, ah, 0, 1, 2, 3, 4, 5, 6, 7);
        fb[h] = __builtin_shufflevector(bl, bh, 0, 1, 2, 3, 4, 5, 6, 7);
    }

    // padded tap table (indices 15..25 hold g[0..10], rest zero)
    if (tid >= 64 && tid < 112) {
        int t = tid - 64;
        int k = t - 15;
        int kc = k < 0 ? 0 : (k > 10 ? 10 : k);      // clamp: no speculative OOB
        gpad[t] = (k == kc) ? (_Float16)gw.g[kc] : (_Float16)0.f;
    }

    // Fused patch-max: tile needs patches rows 2by-1..2by+3, cols 4bx-1..4bx+5
    // (5x7 = 35 patches). 560 tasks = 35 patches x 16 rows; each task
    // max-reduces one 16-int mask row; the 16 consecutive threads sharing a
    // patch shfl-reduce and lane (tid&15)==0 stores pm[p]. Every pm slot is
    // written (rounds cover p=0..15, 16..31, 32..34) -- no init, no atomics.
    {
        const int* mbase = mask + ((size_t)(bc / 3) << 18);
        #pragma unroll
        for (int T = tid; T < 560; T += 256) {
            int p = T >> 4, i = T & 15;
            int pr = 2 * (int)blockIdx.y - 1 + p / 7;
            int pc = 4 * (int)blockIdx.x - 1 + p % 7;
            int m = 0;
            if (pr >= 0 && pr < 32 && pc >= 0 && pc < 32) {
                const int4* r4 = (const int4*)(mbase + (((pr << 4) + i) << 9) + (pc << 4));
                int4 v0 = r4[0], v1 = r4[1], v2 = r4[2], v3 = r4[3];
                m = max(max(max(v0.x, v0.y), max(v0.z, v0.w)),
                        max(max(v1.x, v1.y), max(v1.z, v1.w)));
                m = max(m, max(max(max(v2.x, v2.y), max(v2.z, v2.w)),
                               max(max(v3.x, v3.y), max(v3.z, v3.w))));
            }
            m = max(m, __shfl_xor(m, 1));
            m = max(m, __shfl_xor(m, 2));
            m = max(m, __shfl_xor(m, 4));
            m = max(m, __shfl_xor(m, 8));
            if ((tid & 15) == 0) pm[p] = m ? 1 : 0;
        }
    }
    __syncthreads();

    // 3x3 dilation from the pm grid (pm is offset by (-1,-1) patches)
    if (tid < 15) {
        int tr = tid / 5, tc = tid - tr * 5;
        int acc = 0;
        #pragma unroll
        for (int dy = 0; dy < 3; ++dy)
            #pragma unroll
            for (int dx = 0; dx < 3; ++dx) acc |= pm[(tr + dy) * 7 + tc + dx];
        sdil[tid] = acc ? 1 : 0;
    }
    __syncthreads();

    // Toeplitz A-frag (shared by all passes): A[m=nidx][k=quad*8+j] = g[k-m].
    f16x8 af;
    {
        const _Float16* gp = &gpad[quad * 8 - nidx + 15];
        #pragma unroll
        for (int j = 0; j < 8; ++j) af[j] = gp[j];
    }

    // Transpose-buffer addresses (per-wave region sHT[wv], 40 B rows):
    // write: lane(quad,nidx) holds (x' = 4*quad+r, y = 16g+nidx) -> word at
    //        row 16g+nidx, col 4*quad  (one b64 per g; +320 f16 per g).
    _Float16* wp = &sHT[wv][nidx][quad * 4];
    // tr read: lane(q,m) fetches word (y = 8q + (m>>2) [+4h +16G], w = m&3).
    lds_cf16* rp = (lds_cf16*)&sHT[wv][8 * quad + (nidx >> 2)][4 * (nidx & 3)];

    // Per map: 3 H-MFMAs -> row-major sHT -> tr-read -> 2 V-MFMAs.
    f32x4 acca[4], accb[4];
    #pragma unroll
    for (int mm = 0; mm < 4; ++mm) {
        f16x8 f0, f1, f2;
        if (mm == 0)      { f0 = fa[0]; f1 = fa[1]; f2 = fa[2]; }
        else if (mm == 1) { f0 = fb[0]; f1 = fb[1]; f2 = fb[2]; }
        else if (mm == 2) { f0 = fa[0] * fb[0]; f1 = fa[1] * fb[1]; f2 = fa[2] * fb[2]; }
        else              { f0 = fa[0] * fa[0] + fb[0] * fb[0];
                            f1 = fa[1] * fa[1] + fb[1] * fb[1];
                            f2 = fa[2] * fa[2] + fb[2] * fb[2]; }
        f32x4 z = {0.f, 0.f, 0.f, 0.f};
        f32x4 c0 = mfma_f16(af, f0, z);   // H-conv rows 0..15
        f32x4 c1 = mfma_f16(af, f1, z);   // rows 16..31
        f32x4 c2 = mfma_f16(af, f2, z);   // rows 32..47
        // C layout: x' = quad*4+r (consecutive r!), y = data row = nidx + 16g
        *(f16x4*)(wp)       = __builtin_convertvector(c0, f16x4);
        *(f16x4*)(wp + 320) = __builtin_convertvector(c1, f16x4);
        *(f16x4*)(wp + 640) = __builtin_convertvector(c2, f16x4);
        // V-pass B-frags via HW transpose read. offsets (bytes):
        //   group a (y=0..31):  h0 -> 0,   h1 -> +4 rows = 160
        //   group b (y=16..47): h0 -> 640, h1 -> 800
        f16x4 r0, r1, r2, r3;
        asm volatile("ds_read_b64_tr_b16 %0, %4 offset:0\n\t"
                     "ds_read_b64_tr_b16 %1, %4 offset:160\n\t"
                     "ds_read_b64_tr_b16 %2, %4 offset:640\n\t"
                     "ds_read_b64_tr_b16 %3, %4 offset:800"
                     : "=&v"(r0), "=&v"(r1), "=&v"(r2), "=&v"(r3)
                     : "v"(rp) : "memory");
        asm volatile("s_waitcnt lgkmcnt(0)" ::: "memory");
        __builtin_amdgcn_sched_barrier(0);   // rule #18: keep MFMA after the wait
        f16x8 hba = __builtin_shufflevector(r0, r1, 0, 1, 2, 3, 4, 5, 6, 7);
        f16x8 hbb = __builtin_shufflevector(r2, r3, 0, 1, 2, 3, 4, 5, 6, 7);
        acca[mm] = mfma_f16(af, hba, z);
        accb[mm] = mfma_f16(af, hbb, z);
    }

    // Epilogue: lane holds 4 maps x 8 pixels: group a at y = y0+quad*4+r,
    // group b at y = y0+16+quad*4+r, x = x0+cb+nidx. f32x2 packs (a,b).
    const float C1v = 1e-4f, C2v = 9e-4f;  // L = 1 (inputs uniform [0,1))
    const float cm = gw.cm;
    float lsum = 0.f;
    {
        const int xl = cb + nidx;
        const int x = x0 + xl;
        if (x < OUTD) {
            const int lc0 = xl >> 4, lc1 = (xl + 10) >> 4;
            const int p0 = sdil[lc0]      & sdil[lc1];
            const int p1 = sdil[5 + lc0]  & sdil[5 + lc1];
            const int p2 = sdil[10 + lc0] & sdil[10 + lc1];

            #pragma unroll
            for (int r = 0; r < 4; ++r) {
                int q4r = quad * 4 + r;
                int cond = q4r < 6;   // window stays within patch-row stripe
                int va = cond ? p0 : (p0 & p1);              // group a always in-range
                int yb = y0 + 16 + q4r;
                int vb = cond ? p1 : (p1 & p2);
                vb = (yb < OUTD) ? vb : 0;
                f32x2 mu1 = {acca[0][r], accb[0][r]};
                f32x2 mu2 = {acca[1][r], accb[1][r]};
                f32x2 Sab = {acca[2][r], accb[2][r]};
                f32x2 Sss = {acca[3][r], accb[3][r]};
                mu1 *= cm; mu2 *= cm; Sab *= cm; Sss *= cm;
                f32x2 mu1s = mu1 * mu1, mu2s = mu2 * mu2, mu12 = mu1 * mu2;
                f32x2 sg12 = Sab - mu12;
                f32x2 sigS = Sss - mu1s - mu2s;
                f32x2 num = (2.f * mu12 + C1v) * (2.f * sg12 + C2v);
                f32x2 den = (mu1s + mu2s + C1v) * (sigS + C2v);
                if (va) lsum += __fdividef(num[0], den[0]);
                if (vb) lsum += __fdividef(num[1], den[1]);
            }
        }
    }

    // block reduction -> one float partial per block (deterministic, no atomics)
    #pragma unroll
    for (int off = 32; off >= 1; off >>= 1) lsum += __shfl_xor(lsum, off);
    if ((tid & 63) == 0) wsum[tid >> 6] = lsum;
    __syncthreads();
    if (tid == 0)
        partial[((int)blockIdx.z * GY + (int)blockIdx.y) * GX + (int)blockIdx.x] =
            wsum[0] + wsum[1] + wsum[2] + wsum[3];
}

// Kernel 2: reduce partials, divide by element count (deterministic order)
__global__ __launch_bounds__(256) void finalize_kernel(const float* __restrict__ partial,
                                                       float* __restrict__ out) {
    __shared__ double sd[256];
    double s = 0.0;
    const f32x4* p4 = (const f32x4*)partial;
    for (int i = threadIdx.x; i < NPARTIAL / 4; i += 256) {
        f32x4 vv = p4[i];
        s += (double)vv.x + (double)vv.y + (double)vv.z + (double)vv.w;
    }
    sd[threadIdx.x] = s;
    __syncthreads();
    for (int st = 128; st >= 1; st >>= 1) {
        if (threadIdx.x < st) sd[threadIdx.x] += sd[threadIdx.x + st];
        __syncthreads();
    }
    if (threadIdx.x == 0) out[0] = (float)(sd[0] / 12096192.0);  // 16*3*502*502
}

// Round a positive normal double to the nearest fp16-representable float (RTNE).
static inline float fp16_rtne(double x) {
    float f = (float)x;
    uint32_t u; memcpy(&u, &f, 4);
    // drop 13 mantissa bits (23 -> 10), RTNE with carry into exponent
    u = (u + 0xFFFu + ((u >> 13) & 1u)) & ~0x1FFFu;
    memcpy(&f, &u, 4);
    return f;
}

extern "C" void kernel_launch(void* const* d_in, const int* in_sizes, int n_in,
                              void* d_out, int out_size, void* d_ws, size_t ws_size,
                              hipStream_t stream) {
    const float* img1 = (const float*)d_in[0];
    const float* img2 = (const float*)d_in[1];
    const int*   mask = (const int*)d_in[2];
    float* out = (float*)d_out;

    char* ws = (char*)d_ws;
    float* partial = (float*)ws;                              // 6144 floats

    // Gaussian(sigma=1.5), normalized in double, then each tap rounded to
    // fp16 (RTNE). cm = 1/(sum of rounded taps)^2 removes the systematic
    // scale error of fp16 conv weights (applied to all 4 maps in epilogue).
    GW gw;
    double gd[NTAP], gsum = 0.0;
    for (int i = 0; i < NTAP; ++i) {
        double x = (double)(i - 5);
        gd[i] = exp(-(x * x) / 4.5);
        gsum += gd[i];
    }
    double wsumr = 0.0;
    for (int i = 0; i < NTAP; ++i) {
        gw.g[i] = fp16_rtne(gd[i] / gsum);
        wsumr += (double)gw.g[i];
    }
    gw.cm = (float)(1.0 / (wsumr * wsumr));

    ssim_fused<<<dim3(GX, GY, 48), 256, 0, stream>>>(img1, img2, mask, partial, gw);
    finalize_kernel<<<1, 256, 0, stream>>>(partial, out);
}

// Round 9
// 166.100 us; speedup vs baseline: 2.4605x; 1.0281x over previous
//
#include <hip/hip_runtime.h>
#include <cmath>
#include <cstdint>
#include <cstring>

// Problem constants (B,C,H,W) = (16,3,512,512), window 11, patch 16.
#define OUTD 502          // 512 - 11 + 1
#define TSX  64           // output tile width
#define TSY  32           // output tile height (2 groups of 16)
#define HT2P   20         // transpose buffer row pitch (f16): 40 B
#define NTAP 11
#define GX   8            // ceil(502/64)
#define GY   16           // ceil(502/32)
#define NPARTIAL (48 * GY * GX)   // 6144

typedef float    f32x2 __attribute__((ext_vector_type(2)));
typedef float    f32x4 __attribute__((ext_vector_type(4)));
typedef _Float16 f16x4 __attribute__((ext_vector_type(4)));
typedef _Float16 f16x8 __attribute__((ext_vector_type(8)));
typedef __attribute__((address_space(3))) const _Float16 lds_cf16;

struct GW { float g[NTAP]; float cm; };  // g: fp16-rounded weights; cm = 1/(sum g)^2

__device__ __forceinline__ f32x4 mfma_f16(f16x8 a, f16x8 b, f32x4 c) {
    return __builtin_amdgcn_mfma_f32_16x16x32_f16(a, b, c, 0, 0, 0);
}

// Kernel 1: per-patch (16x16) max of the int mask -> small[b][32][32]
__global__ __launch_bounds__(256) void patch_max_kernel(const int* __restrict__ mask,
                                                        int* __restrict__ smallbuf) {
    const int py = blockIdx.x;   // 0..31 patch row
    const int b  = blockIdx.y;   // 0..15 image
    const int tid = threadIdx.x;
    const int lane = tid & 63, wv = tid >> 6;
    const int4* m4 = (const int4*)(mask + ((size_t)b << 18) + (size_t)py * 16 * 512);
    #pragma unroll
    for (int j = 0; j < 8; ++j) {
        int px  = wv + 4 * j;
        int row = lane >> 2, q = lane & 3;
        int4 v = m4[row * 128 + px * 4 + q];
        int mx = max(max(v.x, v.y), max(v.z, v.w));
        #pragma unroll
        for (int off = 32; off >= 1; off >>= 1) mx = max(mx, __shfl_xor(mx, off));
        if (lane == 0) smallbuf[((b << 5) + py) * 32 + px] = mx;
    }
}

// Kernel 2: MFMA separable-Gaussian SSIM over a 64x32 output tile.
// R9 revision. R8 attribution: patch-max fusion was a net loss (dispatch
// 62.7->72.2 us to save ~5 us launch) -> REVERTED to R6's 3-kernel form
// (best total 166.3). Remaining bottleneck in the 62.7 us dispatch: all
// pipes <50% busy; the per-map loop serializes a full DS round-trip
// (H-MFMA -> 3 ds_write_b64 -> 4 tr_read -> lgkmcnt(0) ~120+cyc stall ->
// V-MFMA) 4x per wave with only ~3.5 waves/SIMD to cover it. Fix:
// SOFTWARE-PIPELINE the map loop over a DOUBLE-BUFFERED sHT (2 x 7.7 KB):
// per iter, issue tr_reads(mm) from buf[mm&1] FIRST, then compute map mm+1's
// f-frags + 3 H-MFMAs + cvt + writes into the OTHER buffer (~150 cyc of
// VALU/MFMA covering the read latency), then s_waitcnt lgkmcnt(3) -- LDS
// completes in-order, so <=3 outstanding means the 3 just-issued writes may
// remain but all 4 reads are done -- then the 2 V-MFMAs. WAR on buffer reuse
// is safe by in-order DS issue; both asm blocks carry "memory" so compiler
// stores cannot migrate across the reads (which would break the count);
// sched_barrier(0) after each wait keeps the V-MFMAs below it (rule #18).
__global__ __launch_bounds__(256) void ssim_kernel(const float* __restrict__ img1,
                                                   const float* __restrict__ img2,
                                                   const int* __restrict__ smallbuf,
                                                   float* __restrict__ partial, GW gw) {
    __shared__ __align__(16) _Float16 sHT[2][4][48][HT2P];  // 15360 B, dbuf x wave
    __shared__ _Float16 gpad[48];               // zero-padded taps: gpad[15+i]=g[i]
    __shared__ int sdil[15];                    // 3 patch-rows x 5 patch-cols
    __shared__ float wsum[4];

    const int tid  = threadIdx.x;
    const int wv   = tid >> 6, lane = tid & 63;
    const int nidx = lane & 15, quad = lane >> 4;
    const int x0 = blockIdx.x * TSX, y0 = blockIdx.y * TSY;
    const int bc = blockIdx.z;               // b*3 + c
    const size_t base = (size_t)bc << 18;    // *512*512

    // This wave handles output cols cb..cb+15 of the tile.
    const int cb = 16 * wv;

    // Direct global->reg B-frags (issued early; consumed after the sync).
    // Clamps: col base <=504 (8 f32 stay in-row), row <=511. Clamped data
    // only feeds zero-weighted taps or discarded outputs, and is finite.
    int gxc = x0 + cb + quad * 8; gxc = gxc > 504 ? 504 : gxc;
    f16x8 fa[3], fb[3];
    #pragma unroll
    for (int h = 0; h < 3; ++h) {
        int gy = y0 + 16 * h + nidx; gy = gy > 511 ? 511 : gy;
        const float* p1 = img1 + base + ((size_t)gy << 9) + gxc;
        const float* p2 = img2 + base + ((size_t)gy << 9) + gxc;
        f32x4 alo = *(const f32x4*)p1, ahi = *(const f32x4*)(p1 + 4);
        f32x4 blo = *(const f32x4*)p2, bhi = *(const f32x4*)(p2 + 4);
        f16x4 al = __builtin_convertvector(alo, f16x4);
        f16x4 ah = __builtin_convertvector(ahi, f16x4);
        f16x4 bl = __builtin_convertvector(blo, f16x4);
        f16x4 bh = __builtin_convertvector(bhi, f16x4);
        fa[h] = __builtin_shufflevector(al, ah, 0, 1, 2, 3, 4, 5, 6, 7);
        fb[h] = __builtin_shufflevector(bl, bh, 0, 1, 2, 3, 4, 5, 6, 7);
    }

    // padded tap table (indices 15..25 hold g[0..10], rest zero)
    if (tid < 48) {
        int k = tid - 15;
        int kc = k < 0 ? 0 : (k > 10 ? 10 : k);      // clamp: no speculative OOB
        gpad[tid] = (k == kc) ? (_Float16)gw.g[kc] : (_Float16)0.f;
    }

    // fused 3x3 dilation lookup: tile spans patch rows 2*by .. 2*by+2 (window
    // reaches y0+41), patch cols bx*4 .. bx*4+4.
    if (tid >= 192 && tid < 207) {
        int t = tid - 192;
        int tr = t / 5, tc = t - tr * 5;
        int pr = 2 * (int)blockIdx.y + tr;
        int pc = (int)blockIdx.x * 4 + tc;
        int acc = 0;
        if (pr < 32 && pc < 32) {
            const int* sb = smallbuf + ((bc / 3) << 10);
            #pragma unroll
            for (int dy = -1; dy <= 1; ++dy)
                #pragma unroll
                for (int dx = -1; dx <= 1; ++dx) {
                    int ny = pr + dy, nx = pc + dx;
                    if (ny >= 0 && ny < 32 && nx >= 0 && nx < 32) acc |= sb[(ny << 5) + nx];
                }
        }
        sdil[t] = acc ? 1 : 0;
    }
    __syncthreads();

    // Toeplitz A-frag (shared by all passes): A[m=nidx][k=quad*8+j] = g[k-m].
    f16x8 af;
    {
        const _Float16* gp = &gpad[quad * 8 - nidx + 15];
        #pragma unroll
        for (int j = 0; j < 8; ++j) af[j] = gp[j];
    }

    // Transpose-buffer addresses (per-wave regions, 40 B rows), double-buffered:
    // write: lane(quad,nidx) holds (x' = 4*quad+r, y = 16g+nidx) -> word at
    //        row 16g+nidx, col 4*quad (one b64 per g; +320 f16 per g).
    _Float16* wp0 = &sHT[0][wv][nidx][quad * 4];
    _Float16* wp1 = &sHT[1][wv][nidx][quad * 4];
    // tr read: lane(q,m) fetches word (y = 8q + (m>>2) [+4h +16G], w = m&3).
    lds_cf16* rp0 = (lds_cf16*)&sHT[0][wv][8 * quad + (nidx >> 2)][4 * (nidx & 3)];
    lds_cf16* rp1 = (lds_cf16*)&sHT[1][wv][8 * quad + (nidx >> 2)][4 * (nidx & 3)];

    const f32x4 z = {0.f, 0.f, 0.f, 0.f};

#define MAKE_F(MM, F0, F1, F2)                                                 \
    if (MM == 0)      { F0 = fa[0]; F1 = fa[1]; F2 = fa[2]; }                  \
    else if (MM == 1) { F0 = fb[0]; F1 = fb[1]; F2 = fb[2]; }                  \
    else if (MM == 2) { F0 = fa[0] * fb[0]; F1 = fa[1] * fb[1];                \
                        F2 = fa[2] * fb[2]; }                                  \
    else              { F0 = fa[0] * fa[0] + fb[0] * fb[0];                    \
                        F1 = fa[1] * fa[1] + fb[1] * fb[1];                    \
                        F2 = fa[2] * fa[2] + fb[2] * fb[2]; }

#define H_STAGE(MM, WP) do {                                                   \
        f16x8 f0, f1, f2;                                                      \
        MAKE_F(MM, f0, f1, f2)                                                 \
        f32x4 c0 = mfma_f16(af, f0, z);   /* H-conv rows 0..15  */             \
        f32x4 c1 = mfma_f16(af, f1, z);   /* rows 16..31        */             \
        f32x4 c2 = mfma_f16(af, f2, z);   /* rows 32..47        */             \
        *(f16x4*)(WP)       = __builtin_convertvector(c0, f16x4);              \
        *(f16x4*)(WP + 320) = __builtin_convertvector(c1, f16x4);              \
        *(f16x4*)(WP + 640) = __builtin_convertvector(c2, f16x4);              \
    } while (0)

    // Pipelined map loop: prologue stages map 0; each iter issues tr_reads(mm)
    // first, stages map mm+1 into the other buffer, then waits lgkmcnt(3)
    // (in-order LDS: only the 3 fresh writes may remain) and runs V-MFMAs.
    f32x4 acca[4], accb[4];
    H_STAGE(0, wp0);
    #pragma unroll
    for (int mm = 0; mm < 4; ++mm) {
        // V-pass B-frags via HW transpose read. offsets (bytes):
        //   group a (y=0..31):  h0 -> 0,   h1 -> +4 rows = 160
        //   group b (y=16..47): h0 -> 640, h1 -> 800
        f16x4 r0, r1, r2, r3;
        asm volatile("ds_read_b64_tr_b16 %0, %4 offset:0\n\t"
                     "ds_read_b64_tr_b16 %1, %4 offset:160\n\t"
                     "ds_read_b64_tr_b16 %2, %4 offset:640\n\t"
                     "ds_read_b64_tr_b16 %3, %4 offset:800"
                     : "=&v"(r0), "=&v"(r1), "=&v"(r2), "=&v"(r3)
                     : "v"((mm & 1) ? rp1 : rp0) : "memory");
        // Stage next map while the reads are in flight.
        if (mm == 0)      { H_STAGE(1, wp1); }
        else if (mm == 1) { H_STAGE(2, wp0); }
        else if (mm == 2) { H_STAGE(3, wp1); }
        if (mm < 3) asm volatile("s_waitcnt lgkmcnt(3)" ::: "memory");
        else        asm volatile("s_waitcnt lgkmcnt(0)" ::: "memory");
        __builtin_amdgcn_sched_barrier(0);   // rule #18: keep MFMA after the wait
        f16x8 hba = __builtin_shufflevector(r0, r1, 0, 1, 2, 3, 4, 5, 6, 7);
        f16x8 hbb = __builtin_shufflevector(r2, r3, 0, 1, 2, 3, 4, 5, 6, 7);
        acca[mm] = mfma_f16(af, hba, z);
        accb[mm] = mfma_f16(af, hbb, z);
    }
#undef H_STAGE
#undef MAKE_F

    // Epilogue: lane holds 4 maps x 8 pixels: group a at y = y0+quad*4+r,
    // group b at y = y0+16+quad*4+r, x = x0+cb+nidx. f32x2 packs (a,b).
    const float C1v = 1e-4f, C2v = 9e-4f;  // L = 1 (inputs uniform [0,1))
    const float cm = gw.cm;
    float lsum = 0.f;
    {
        const int xl = cb + nidx;
        const int x = x0 + xl;
        if (x < OUTD) {
            const int lc0 = xl >> 4, lc1 = (xl + 10) >> 4;
            const int p0 = sdil[lc0]      & sdil[lc1];
            const int p1 = sdil[5 + lc0]  & sdil[5 + lc1];
            const int p2 = sdil[10 + lc0] & sdil[10 + lc1];

            #pragma unroll
            for (int r = 0; r < 4; ++r) {
                int q4r = quad * 4 + r;
                int cond = q4r < 6;   // window stays within patch-row stripe
                int va = cond ? p0 : (p0 & p1);              // group a always in-range
                int yb = y0 + 16 + q4r;
                int vb = cond ? p1 : (p1 & p2);
                vb = (yb < OUTD) ? vb : 0;
                f32x2 mu1 = {acca[0][r], accb[0][r]};
                f32x2 mu2 = {acca[1][r], accb[1][r]};
                f32x2 Sab = {acca[2][r], accb[2][r]};
                f32x2 Sss = {acca[3][r], accb[3][r]};
                mu1 *= cm; mu2 *= cm; Sab *= cm; Sss *= cm;
                f32x2 mu1s = mu1 * mu1, mu2s = mu2 * mu2, mu12 = mu1 * mu2;
                f32x2 sg12 = Sab - mu12;
                f32x2 sigS = Sss - mu1s - mu2s;
                f32x2 num = (2.f * mu12 + C1v) * (2.f * sg12 + C2v);
                f32x2 den = (mu1s + mu2s + C1v) * (sigS + C2v);
                if (va) lsum += __fdividef(num[0], den[0]);
                if (vb) lsum += __fdividef(num[1], den[1]);
            }
        }
    }

    // block reduction -> one float partial per block (deterministic, no atomics)
    #pragma unroll
    for (int off = 32; off >= 1; off >>= 1) lsum += __shfl_xor(lsum, off);
    if ((tid & 63) == 0) wsum[tid >> 6] = lsum;
    __syncthreads();
    if (tid == 0)
        partial[((int)blockIdx.z * GY + (int)blockIdx.y) * GX + (int)blockIdx.x] =
            wsum[0] + wsum[1] + wsum[2] + wsum[3];
}

// Kernel 3: reduce partials, divide by element count (deterministic order)
__global__ __launch_bounds__(256) void finalize_kernel(const float* __restrict__ partial,
                                                       float* __restrict__ out) {
    __shared__ double sd[256];
    double s = 0.0;
    const f32x4* p4 = (const f32x4*)partial;
    for (int i = threadIdx.x; i < NPARTIAL / 4; i += 256) {
        f32x4 vv = p4[i];
        s += (double)vv.x + (double)vv.y + (double)vv.z + (double)vv.w;
    }
    sd[threadIdx.x] = s;
    __syncthreads();
    for (int st = 128; st >= 1; st >>= 1) {
        if (threadIdx.x < st) sd[threadIdx.x] += sd[threadIdx.x + st];
        __syncthreads();
    }
    if (threadIdx.x == 0) out[0] = (float)(sd[0] / 12096192.0);  // 16*3*502*502
}

// Round a positive normal double to the nearest fp16-representable float (RTNE).
static inline float fp16_rtne(double x) {
    float f = (float)x;
    uint32_t u; memcpy(&u, &f, 4);
    // drop 13 mantissa bits (23 -> 10), RTNE with carry into exponent
    u = (u + 0xFFFu + ((u >> 13) & 1u)) & ~0x1FFFu;
    memcpy(&f, &u, 4);
    return f;
}

extern "C" void kernel_launch(void* const* d_in, const int* in_sizes, int n_in,
                              void* d_out, int out_size, void* d_ws, size_t ws_size,
                              hipStream_t stream) {
    const float* img1 = (const float*)d_in[0];
    const float* img2 = (const float*)d_in[1];
    const int*   mask = (const int*)d_in[2];
    float* out = (float*)d_out;

    char* ws = (char*)d_ws;
    float* partial  = (float*)ws;                        // 6144 floats
    int*   smallbuf = (int*)(ws + NPARTIAL * 4);         // 16*32*32 ints

    // Gaussian(sigma=1.5), normalized in double, then each tap rounded to
    // fp16 (RTNE). cm = 1/(sum of rounded taps)^2 removes the systematic
    // scale error of fp16 conv weights (applied to all 4 maps in epilogue).
    GW gw;
    double gd[NTAP], gsum = 0.0;
    for (int i = 0; i < NTAP; ++i) {
        double x = (double)(i - 5);
        gd[i] = exp(-(x * x) / 4.5);
        gsum += gd[i];
    }
    double wsumr = 0.0;
    for (int i = 0; i < NTAP; ++i) {
        gw.g[i] = fp16_rtne(gd[i] / gsum);
        wsumr += (double)gw.g[i];
    }
    gw.cm = (float)(1.0 / (wsumr * wsumr));

    patch_max_kernel<<<dim3(32, 16), 256, 0, stream>>>(mask, smallbuf);
    ssim_kernel<<<dim3(GX, GY, 48), 256, 0, stream>>>(img1, img2, smallbuf, partial, gw);
    finalize_kernel<<<1, 256, 0, stream>>>(partial, out);
}